// Round 2
// baseline (68.473 us; speedup 1.0000x reference)
//
#include <hip/hip_runtime.h>

// WiSARD inference: B=4096 samples, ENTRY=1024 bits, TUPLE=16, CLASSES=10,
// NEURONS=64, ADDR_SPACE=2^16.
// out[b][c] = sum_n ram[c][n][addr(b,c,n)],
// addr(b,c,n) = sum_t samples[b][tm[c][n*16+t]] << (15-t)
//
// ram values are exactly 0.0/1.0 -> bit-pack ram (168MB f32 -> 5.25MB bits)
// each launch, then classify gathers single bits from an L2-resident table.

#define BATCH      4096
#define ENTRY      1024
#define TUPLE      16
#define CLASSES    10
#define NEURONS    64

// ---------------- Kernel 1: bit-pack samples ----------------
// One wave per sample. 16 ballot iterations of 64 bits each -> 1024 bits.
__global__ __launch_bounds__(256) void pack_kernel(
    const int* __restrict__ samples,
    unsigned long long* __restrict__ packed64)
{
    const int gtid = blockIdx.x * 256 + threadIdx.x;
    const int wave = gtid >> 6;       // sample index, 0..4095
    const int lane = gtid & 63;
    const int* sp = samples + (size_t)wave * ENTRY;
#pragma unroll
    for (int t = 0; t < 16; ++t) {
        int v = sp[t * 64 + lane];
        unsigned long long m = __ballot(v & 1);
        if (lane == 0) packed64[wave * 16 + t] = m;
    }
}

// ---------------- Kernel 2: bit-pack ram ----------------
// ram is [CLASSES][NEURONS][65536] f32 with values 0.0/1.0.
// rambits64[i] bit L = (ram[i*64+L] != 0).
// One wave per 256 floats (4 ballot rounds). 163840 waves, 4 waves/block.
__global__ __launch_bounds__(256) void rampack_kernel(
    const float* __restrict__ ram,
    unsigned long long* __restrict__ rambits64)
{
    const int gtid = blockIdx.x * 256 + threadIdx.x;
    const int wave = gtid >> 6;       // 0 .. 163839
    const int lane = gtid & 63;
    const float* rp = ram + (size_t)wave * 256;
#pragma unroll
    for (int t = 0; t < 4; ++t) {
        float f = rp[t * 64 + lane];
        unsigned long long m = __ballot(f != 0.0f);
        if (lane == 0) rambits64[wave * 4 + t] = m;
    }
}

// ---------------- Kernel 3: classify ----------------
// One wave per (sample, class). lane = neuron.
// Gather one uint32 word from the 5.25MB packed ram; sum over neurons via
// ballot+popcount.
__global__ __launch_bounds__(256) void wisard_kernel(
    const int* __restrict__ tm,            // [CLASSES][ENTRY]
    const unsigned* __restrict__ rambits,  // [CLASSES*NEURONS][2048] words
    const unsigned* __restrict__ packed,   // [BATCH][32]
    float* __restrict__ out)               // [BATCH][CLASSES]
{
    const int tid  = threadIdx.x;
    const int lane = tid & 63;           // neuron index
    const int wid  = tid >> 6;           // wave-in-block 0..3
    const int bid  = blockIdx.x;
    const int c    = bid >> 10;                    // class (1024 blocks/class)
    const int s    = ((bid & 1023) << 2) | wid;    // sample

    // 16 tuple indices for this (class, neuron): lane-contiguous 64B loads.
    const int4* tmp4 = reinterpret_cast<const int4*>(tm + c * ENTRY + lane * TUPLE);
    const int4 t0 = tmp4[0];
    const int4 t1 = tmp4[1];
    const int4 t2 = tmp4[2];
    const int4 t3 = tmp4[3];

    // Each lane holds one packed word of this wave's sample (words 0..31,
    // duplicated across the two half-waves). Arbitrary words via shfl.
    const unsigned myword = packed[s * 32 + (lane & 31)];

    unsigned addr = 0;
#define WSTEP(E)                                                 \
    {                                                            \
        const int  w_   = (E) >> 5;                              \
        const int  b_   = (E) & 31;                              \
        const unsigned word_ = (unsigned)__shfl((int)myword, w_);\
        addr = (addr << 1) | ((word_ >> b_) & 1u);               \
    }
    WSTEP(t0.x) WSTEP(t0.y) WSTEP(t0.z) WSTEP(t0.w)
    WSTEP(t1.x) WSTEP(t1.y) WSTEP(t1.z) WSTEP(t1.w)
    WSTEP(t2.x) WSTEP(t2.y) WSTEP(t2.z) WSTEP(t2.w)
    WSTEP(t3.x) WSTEP(t3.y) WSTEP(t3.z) WSTEP(t3.w)
#undef WSTEP

    // Gather one word (2048 words per neuron table), extract the bit.
    const unsigned word = rambits[(((unsigned)(c * NEURONS + lane)) << 11) | (addr >> 5)];
    const unsigned bit  = (word >> (addr & 31)) & 1u;

    // Sum over the 64 neurons: ballot + popcount.
    const unsigned long long m = __ballot(bit != 0u);
    if (lane == 0) out[s * CLASSES + c] = (float)__popcll(m);
}

extern "C" void kernel_launch(void* const* d_in, const int* in_sizes, int n_in,
                              void* d_out, int out_size, void* d_ws, size_t ws_size,
                              hipStream_t stream)
{
    const int*   samples = (const int*)d_in[0];
    const int*   tm      = (const int*)d_in[1];
    const float* ram     = (const float*)d_in[2];
    float*       out     = (float*)d_out;

    // d_ws layout: [0, 512KB) packed samples; [512KB, 512KB+5.25MB) packed ram.
    unsigned long long* packed64  = (unsigned long long*)d_ws;
    unsigned long long* rambits64 = (unsigned long long*)((char*)d_ws + (512u << 10));

    // Pack samples: 4096 waves -> 1024 blocks.
    pack_kernel<<<BATCH / 4, 256, 0, stream>>>(samples, packed64);

    // Pack ram: 163840 waves -> 40960 blocks.
    rampack_kernel<<<(CLASSES * NEURONS * 65536 / 256) / 4, 256, 0, stream>>>(
        ram, rambits64);

    // Classify: 40960 waves -> 10240 blocks.
    wisard_kernel<<<CLASSES * (BATCH / 4), 256, 0, stream>>>(
        tm, (const unsigned*)rambits64, (const unsigned*)packed64, out);
}

// Round 3
// 67.847 us; speedup vs baseline: 1.0092x; 1.0092x over previous
//
#include <hip/hip_runtime.h>

// WiSARD inference: B=4096, ENTRY=1024, TUPLE=16, CLASSES=10, NEURONS=64,
// ADDR_SPACE=2^16.  out[b][c] = sum_n ram_bit[c][n][addr(b,c,n)]
//
// Pipeline (ram is 0.0/1.0 -> bits):
//  1. packT : samples -> bitT[1024 bitpos][64 sgroup] u64  (bit L = sample sg*64+L)
//  2. addr  : bitT + tm -> addrT[640 cn][4096 s] u16   (coalesced, broadcast loads)
//  3. gather: block=(cn,half): stream 128KB of ram as float4 -> 4KB LDS bit table,
//             look up 4096 addrs from LDS, ballot -> partial[cn][h][64] u64 masks
//  4. reduce: OR halves, ballot-popcount over neurons -> out[4096][10] f32

#define BATCH   4096
#define ENTRY   1024
#define TUPLE   16
#define CLASSES 10
#define NEURONS 64
#define CN      (CLASSES * NEURONS)   // 640
#define ADDRSP  65536

typedef unsigned long long u64;
typedef unsigned int       u32;
typedef unsigned short     u16;

// ---------------- Kernel 1: bit-transpose pack ----------------
// grid 1024 blocks x 256. block -> (sgroup, j16); wave covers 16 bit-positions.
__global__ __launch_bounds__(256) void packT_kernel(
    const int* __restrict__ samples, u64* __restrict__ bitT)
{
    const int b    = blockIdx.x;
    const int sg   = b >> 4;            // sample group 0..63
    const int j16  = b & 15;
    const int w    = threadIdx.x >> 6;
    const int lane = threadIdx.x & 63;
    const int j0   = j16 * 64 + w * 16;
    const int* rp  = samples + (size_t)(sg * 64 + lane) * ENTRY;
#pragma unroll
    for (int k = 0; k < 4; ++k) {
        const int j = j0 + k * 4;
        const int4 v = *reinterpret_cast<const int4*>(rp + j);
        const u64 m0 = __ballot(v.x & 1);
        const u64 m1 = __ballot(v.y & 1);
        const u64 m2 = __ballot(v.z & 1);
        const u64 m3 = __ballot(v.w & 1);
        if (lane == 0) {
            bitT[(j + 0) * 64 + sg] = m0;
            bitT[(j + 1) * 64 + sg] = m1;
            bitT[(j + 2) * 64 + sg] = m2;
            bitT[(j + 3) * 64 + sg] = m3;
        }
    }
}

// ---------------- Kernel 2: address build ----------------
// grid 10240 blocks x 256. block -> (cn, sgq); wave -> sgroup; lane -> sample.
__global__ __launch_bounds__(256) void addr_kernel(
    const int* __restrict__ tm, const u64* __restrict__ bitT,
    u16* __restrict__ addrT)
{
    const int b    = blockIdx.x;
    const int cn   = b >> 4;            // 0..639
    const int sgq  = b & 15;
    const int w    = threadIdx.x >> 6;
    const int lane = threadIdx.x & 63;
    const int sg   = sgq * 4 + w;
    const int c    = cn >> 6;
    const int n    = cn & 63;

    const int* tp = tm + c * ENTRY + n * TUPLE;
    const int4 i0 = reinterpret_cast<const int4*>(tp)[0];
    const int4 i1 = reinterpret_cast<const int4*>(tp)[1];
    const int4 i2 = reinterpret_cast<const int4*>(tp)[2];
    const int4 i3 = reinterpret_cast<const int4*>(tp)[3];

    u32 addr = 0;
#define ASTEP(E)                                                   \
    {                                                              \
        const u64 word_ = bitT[(E) * 64 + sg];                     \
        addr = (addr << 1) | (u32)((word_ >> lane) & 1ull);        \
    }
    ASTEP(i0.x) ASTEP(i0.y) ASTEP(i0.z) ASTEP(i0.w)
    ASTEP(i1.x) ASTEP(i1.y) ASTEP(i1.z) ASTEP(i1.w)
    ASTEP(i2.x) ASTEP(i2.y) ASTEP(i2.z) ASTEP(i2.w)
    ASTEP(i3.x) ASTEP(i3.y) ASTEP(i3.z) ASTEP(i3.w)
#undef ASTEP

    addrT[cn * BATCH + sg * 64 + lane] = (u16)addr;
}

// ---------------- Kernel 3: stream ram -> LDS bits, gather ----------------
// grid 1280 blocks x 256 (5 blocks/CU). block -> (cn, half of 32768 cells).
// LDS layout: per 256-float group g, 4 u64 words (j = float&3 interleave):
//   bit of float f (local) = tbl[(f>>8)*4 + (f&3)] >> ((f>>2)&63)
__global__ __launch_bounds__(256) void gather_kernel(
    const float* __restrict__ ram, const u16* __restrict__ addrT,
    u64* __restrict__ partial)
{
    __shared__ u64 tbl[512];            // 4 KB = 32768 bits
    const int b    = blockIdx.x;
    const int cn   = b >> 1;
    const int h    = b & 1;
    const int w    = threadIdx.x >> 6;
    const int lane = threadIdx.x & 63;

    const float4* rp = reinterpret_cast<const float4*>(
        ram + (size_t)cn * ADDRSP + h * 32768);

#pragma unroll 8
    for (int i = 0; i < 32; ++i) {
        const int g = w * 32 + i;       // 256-float group, 0..127
        const float4 v = rp[g * 64 + lane];
        const u64 m0 = __ballot(v.x != 0.0f);
        const u64 m1 = __ballot(v.y != 0.0f);
        const u64 m2 = __ballot(v.z != 0.0f);
        const u64 m3 = __ballot(v.w != 0.0f);
        if (lane == 0) {
            tbl[g * 4 + 0] = m0;
            tbl[g * 4 + 1] = m1;
            tbl[g * 4 + 2] = m2;
            tbl[g * 4 + 3] = m3;
        }
    }
    __syncthreads();

    const u16* ap = addrT + cn * BATCH;
    u64* pp = partial + (size_t)(cn * 2 + h) * 64;
#pragma unroll
    for (int i = 0; i < 16; ++i) {
        const int sidx = w * 1024 + i * 64 + lane;   // sample index
        const u32 a     = ap[sidx];
        const u32 local = a & 32767u;
        const u64 word  = tbl[(local >> 8) * 4 + (a & 3u)];
        u32 bit = (u32)(word >> ((local >> 2) & 63u)) & 1u;
        bit &= (u32)((a >> 15) == (u32)h);
        const u64 m = __ballot(bit != 0u);
        if (lane == 0) pp[w * 16 + i] = m;
    }
}

// ---------------- Kernel 4: reduce ----------------
// grid 160 blocks x 256 (640 waves). wave -> (class, sgroup); lane -> neuron.
__global__ __launch_bounds__(256) void reduce_kernel(
    const u64* __restrict__ partial, float* __restrict__ out)
{
    const int gid  = blockIdx.x * 4 + (threadIdx.x >> 6);  // 0..639
    const int lane = threadIdx.x & 63;
    const int c    = gid >> 6;
    const int sg   = gid & 63;

    const u64* pp = partial + (size_t)((c * NEURONS + lane) * 2) * 64 + sg;
    const u64 m = pp[0] | pp[64];

    float myv = 0.0f;
#pragma unroll
    for (int b2 = 0; b2 < 64; ++b2) {
        const u64 mb = __ballot((u32)(m >> b2) & 1u);
        if (lane == b2) myv = (float)__popcll(mb);
    }
    out[(sg * 64 + lane) * CLASSES + c] = myv;
}

extern "C" void kernel_launch(void* const* d_in, const int* in_sizes, int n_in,
                              void* d_out, int out_size, void* d_ws, size_t ws_size,
                              hipStream_t stream)
{
    const int*   samples = (const int*)d_in[0];
    const int*   tm      = (const int*)d_in[1];
    const float* ram     = (const float*)d_in[2];
    float*       out     = (float*)d_out;

    // ws layout: bitT [0, 512K) | addrT [512K, 512K+5.25M) | partial (+640K)
    u64* bitT    = (u64*)d_ws;
    u16* addrT   = (u16*)((char*)d_ws + (512u << 10));
    u64* partial = (u64*)((char*)d_ws + (512u << 10) + CN * BATCH * sizeof(u16));

    packT_kernel <<<1024, 256, 0, stream>>>(samples, bitT);
    addr_kernel  <<<CN * 16, 256, 0, stream>>>(tm, bitT, addrT);
    gather_kernel<<<CN * 2, 256, 0, stream>>>(ram, addrT, partial);
    reduce_kernel<<<CN / 4, 256, 0, stream>>>(partial, out);
}

// Round 4
// 50.527 us; speedup vs baseline: 1.3552x; 1.3428x over previous
//
#include <hip/hip_runtime.h>

// WiSARD inference: B=4096, ENTRY=1024, TUPLE=16, CLASSES=10, NEURONS=64.
// out[b][c] = sum_n ram_bit[c][n][addr(b,c,n)]
//
//  1. packT : samples -> bitT[1024 bitpos][64 sgroup] u64 (LDS 64x64 transpose)
//  2. fused : block=(cn,half): stream 128KB of ram (float4) -> 4KB LDS bit tbl;
//             build 4096 addrs for cn from bitT via s_load + cndmask -> 8KB LDS;
//             lookup, ballot -> partial[cn][h][64] u64 masks
//  3. reduce: OR halves, ballot-popcount over neurons -> out[4096][10] f32

#define BATCH   4096
#define ENTRY   1024
#define TUPLE   16
#define CLASSES 10
#define NEURONS 64
#define CN      (CLASSES * NEURONS)   // 640
#define ADDRSP  65536

typedef unsigned long long u64;
typedef unsigned int       u32;
typedef unsigned short     u16;

// ---------------- Kernel 1: bit-transpose pack (coalesced) ----------------
// block (sg, cg): samples rows sg*64..+63, cols cg*64..+63.
// bitT[e][sg] bit L = samples[sg*64+L][e] & 1
__global__ __launch_bounds__(256) void packT_kernel(
    const int* __restrict__ samples, u64* __restrict__ bitT)
{
    __shared__ int tile[64 * 65];          // +1-pad: conflict-free col reads
    const int sg   = blockIdx.x >> 4;
    const int cg   = blockIdx.x & 15;
    const int w    = threadIdx.x >> 6;
    const int lane = threadIdx.x & 63;
    const int t    = threadIdx.x;

    // 64x64 ints = 1024 int4, 4 rounds of 256 threads; wave covers 4 rows
    // x 256B contiguous each -> coalesced.
#pragma unroll
    for (int rnd = 0; rnd < 4; ++rnd) {
        const int idx  = rnd * 256 + t;    // int4 index 0..1023
        const int row  = idx >> 4;
        const int col4 = idx & 15;
        const int4 v = *reinterpret_cast<const int4*>(
            samples + (size_t)(sg * 64 + row) * ENTRY + cg * 64 + col4 * 4);
        int* tp = tile + row * 65 + col4 * 4;
        tp[0] = v.x; tp[1] = v.y; tp[2] = v.z; tp[3] = v.w;
    }
    __syncthreads();

    // transpose: wave w -> columns w*16..w*16+15; lane = sample-in-group
#pragma unroll
    for (int k = 0; k < 16; ++k) {
        const int j = w * 16 + k;
        const u64 m = __ballot(tile[lane * 65 + j] & 1);
        if (lane == 0) bitT[(size_t)(cg * 64 + j) * 64 + sg] = m;
    }
}

// ---------------- Kernel 2: fused stream + addr + lookup ----------------
// grid 1280 blocks x 256 (exactly 5 blocks/CU). block -> (cn, half).
__global__ __launch_bounds__(256) void fused_kernel(
    const int* __restrict__ tm, const float* __restrict__ ram,
    const u64* __restrict__ bitT, u64* __restrict__ partial)
{
    __shared__ u64 tbl[512];               // 4 KB: 32768-bit half-table
    __shared__ u16 addrL[BATCH];           // 8 KB: addresses for this cn
    const int bid  = blockIdx.x;
    const int cn   = bid >> 1;
    const int h    = bid & 1;
    const int c    = cn >> 6;
    const int n    = cn & 63;
    const int lane = threadIdx.x & 63;
    // wave id forced uniform -> scalar addressing in phase A
    const int wu   = __builtin_amdgcn_readfirstlane(threadIdx.x >> 6);

    // ---- Phase B: stream 128 KB half-table -> LDS bit table ----
    // bit of local float f: tbl[(f>>8)*4 + (f&3)] >> ((f>>2)&63)
    const float4* rp = reinterpret_cast<const float4*>(
        ram + (size_t)cn * ADDRSP + h * (ADDRSP / 2));
#pragma unroll 8
    for (int i = 0; i < 32; ++i) {
        const int g = wu * 32 + i;         // 0..127
        const float4 v = rp[g * 64 + lane];
        const u64 m0 = __ballot(v.x != 0.0f);
        const u64 m1 = __ballot(v.y != 0.0f);
        const u64 m2 = __ballot(v.z != 0.0f);
        const u64 m3 = __ballot(v.w != 0.0f);
        if (lane == 0) {
            tbl[g * 4 + 0] = m0; tbl[g * 4 + 1] = m1;
            tbl[g * 4 + 2] = m2; tbl[g * 4 + 3] = m3;
        }
    }

    // ---- Phase A: build addresses for this (c,n); all-scalar loads ----
    const int* tp = tm + c * ENTRY + n * TUPLE;   // uniform -> s_load
    int E[TUPLE];
#pragma unroll
    for (int tt = 0; tt < TUPLE; ++tt) E[tt] = tp[tt];

#pragma unroll
    for (int k = 0; k < 16; ++k) {
        const int sg = wu * 16 + k;        // uniform -> bitT via s_load_dwordx2
        u32 a = 0;
#pragma unroll
        for (int tt = 0; tt < TUPLE; ++tt) {
            const u64 word = bitT[(size_t)E[tt] * 64 + sg];
            u32 bit;
            // word is an SGPR lane-mask: lane L selects bit L in one VALU op
            asm("v_cndmask_b32 %0, 0, 1, %1" : "=v"(bit) : "s"(word));
            a = (a << 1) | bit;
        }
        addrL[sg * 64 + lane] = (u16)a;
    }
    __syncthreads();

    // ---- Phase C: lookup 4096 addresses from LDS ----
    u64* pp = partial + (size_t)cn * 128 + h * 64;
#pragma unroll
    for (int i = 0; i < 16; ++i) {
        const u32 a     = addrL[wu * 1024 + i * 64 + lane];
        const u32 local = a & 32767u;
        const u64 word  = tbl[(local >> 8) * 4 + (a & 3u)];
        u32 bit = (u32)(word >> ((local >> 2) & 63u)) & 1u;
        bit &= (u32)((a >> 15) == (u32)h);
        const u64 m = __ballot(bit != 0u);
        if (lane == 0) pp[wu * 16 + i] = m;
    }
}

// ---------------- Kernel 3: reduce ----------------
// 160 blocks x 256 = 640 waves. wave -> (class, sgroup); lane -> neuron.
__global__ __launch_bounds__(256) void reduce_kernel(
    const u64* __restrict__ partial, float* __restrict__ out)
{
    const int gid  = blockIdx.x * 4 + (threadIdx.x >> 6);  // 0..639
    const int lane = threadIdx.x & 63;
    const int c    = gid >> 6;
    const int sg   = gid & 63;

    const u64* pp = partial + ((size_t)(c * NEURONS + lane)) * 128 + sg;
    const u64 m = pp[0] | pp[64];

    float myv = 0.0f;
#pragma unroll
    for (int b2 = 0; b2 < 64; ++b2) {
        const u64 mb = __ballot((u32)(m >> b2) & 1u);
        if (lane == b2) myv = (float)__popcll(mb);
    }
    out[(sg * 64 + lane) * CLASSES + c] = myv;
}

extern "C" void kernel_launch(void* const* d_in, const int* in_sizes, int n_in,
                              void* d_out, int out_size, void* d_ws, size_t ws_size,
                              hipStream_t stream)
{
    const int*   samples = (const int*)d_in[0];
    const int*   tm      = (const int*)d_in[1];
    const float* ram     = (const float*)d_in[2];
    float*       out     = (float*)d_out;

    // ws: bitT [0, 512K) | partial [512K, 512K+640K)
    u64* bitT    = (u64*)d_ws;
    u64* partial = (u64*)((char*)d_ws + (512u << 10));

    packT_kernel <<<1024, 256, 0, stream>>>(samples, bitT);
    fused_kernel <<<CN * 2, 256, 0, stream>>>(tm, ram, bitT, partial);
    reduce_kernel<<<CN / 4, 256, 0, stream>>>(partial, out);
}